// Round 5
// baseline (515.816 us; speedup 1.0000x reference)
//
#include <hip/hip_runtime.h>
#include <math.h>

#define B_   16
#define N_   4096
#define C_   512
#define CF_  256
#define NH_  8
#define HD_  32
#define FHD_ 128
#define BN_  (B_ * N_)   // 65536
#define EPS_ 1e-4f
#define PI2F 1.5707963267948966f

typedef _Float16 half8 __attribute__((ext_vector_type(8)));
typedef _Float16 half4 __attribute__((ext_vector_type(4)));
typedef float f32x4 __attribute__((ext_vector_type(4)));
typedef unsigned short u16x8 __attribute__((ext_vector_type(8)));

__device__ __forceinline__ float abs_clamp(float t) {
    float a = fminf(fmaxf(fabsf(t), 1e-4f), 1e4f);
    return t > 0.f ? a : (t < 0.f ? -a : 0.f);
}
__device__ __forceinline__ void gld16(const void* g, void* l) {
    __builtin_amdgcn_global_load_lds(
        (const __attribute__((address_space(1))) void*)g,
        (__attribute__((address_space(3))) void*)l, 16, 0, 0);
}

// ---------------------------------------------------------------- SE: mean over tokens + f32->f16 convert of query
// 1024 blocks (4/CU), float4 loads, half4 stores.
__global__ __launch_bounds__(256) void se_sum_kernel(const float* __restrict__ q,
                                                     float* __restrict__ sesum,
                                                     _Float16* __restrict__ q16) {
    int b = blockIdx.x, chunk = blockIdx.y;   // chunk = 64 tokens
    int t = threadIdx.x;
    int c = (t & 127) * 4;
    int tok0 = chunk * 64 + (t >> 7) * 32;
    const float* p = q + ((size_t)b * N_ + tok0) * C_ + c;
    _Float16* o = q16 + ((size_t)b * N_ + tok0) * C_ + c;
    float a0 = 0.f, a1 = 0.f, a2 = 0.f, a3 = 0.f;
#pragma unroll 4
    for (int n = 0; n < 32; n++) {
        float4 v = *(const float4*)(p + (size_t)n * C_);
        a0 += v.x; a1 += v.y; a2 += v.z; a3 += v.w;
        half4 hv;
        hv[0] = (_Float16)v.x; hv[1] = (_Float16)v.y;
        hv[2] = (_Float16)v.z; hv[3] = (_Float16)v.w;
        *(half4*)(o + (size_t)n * C_) = hv;
    }
    atomicAdd(&sesum[b * C_ + c + 0], a0);
    atomicAdd(&sesum[b * C_ + c + 1], a1);
    atomicAdd(&sesum[b * C_ + c + 2], a2);
    atomicAdd(&sesum[b * C_ + c + 3], a3);
}

// ---------------------------------------------------------------- SE: 2-layer MLP + sigmoid
__global__ __launch_bounds__(256) void se_gate_kernel(const float* __restrict__ sesum,
                                                      const float* __restrict__ Wse1,
                                                      const float* __restrict__ Wse2,
                                                      float* __restrict__ segate) {
    __shared__ float sm[C_];
    __shared__ float hm[C_ / 2];
    int b = blockIdx.x, t = threadIdx.x;
    sm[t]       = sesum[b * C_ + t]       * (1.f / N_);
    sm[t + 256] = sesum[b * C_ + t + 256] * (1.f / N_);
    __syncthreads();
    {
        const float* w = Wse1 + (size_t)t * C_;
        float acc = 0.f;
        for (int c2 = 0; c2 < C_; c2++) acc += sm[c2] * w[c2];
        hm[t] = fmaxf(acc, 0.f);
    }
    __syncthreads();
    for (int r = 0; r < 2; r++) {
        int c2 = t + r * 256;
        const float* w2 = Wse2 + (size_t)c2 * (C_ / 2);
        float a2 = 0.f;
        for (int j = 0; j < C_ / 2; j++) a2 += hm[j] * w2[j];
        segate[b * C_ + c2] = 1.f / (1.f + expf(-a2));
    }
}

// ---------------------------------------------------------------- weight convert to f16
__global__ __launch_bounds__(256) void convert_w(const float* __restrict__ Wq,
                                                 const float* __restrict__ Wk,
                                                 const float* __restrict__ Wv,
                                                 const float* __restrict__ Wo,
                                                 _Float16* __restrict__ wcat,
                                                 _Float16* __restrict__ wo16) {
    int i = blockIdx.x * 256 + threadIdx.x;
    if (i < 768 * 512) {
        int r = i >> 9, c = i & 511;
        float w = (r < 256) ? Wq[(size_t)r * 512 + c]
                : (r < 512) ? Wk[(size_t)(r - 256) * 512 + c]
                            : Wv[(size_t)(r - 512) * 512 + c];
        wcat[i] = (_Float16)w;
    } else {
        int j = i - 768 * 512;
        wo16[j] = (_Float16)Wo[j];
    }
}

// ---------------------------------------------------------------- q/k/v projection GEMM
// 256 threads = 4 waves (2Mx2N of 64x64), tile 128M x 128N, K=512, dbuf LDS.
// XCD-chunked swizzle; k/v stored TRANSPOSED [col=256][M=65536].
__global__ __launch_bounds__(256) void gemm_qkv(
    const _Float16* __restrict__ A16, const _Float16* __restrict__ Bw,
    const float* __restrict__ bq, const float* __restrict__ bk, const float* __restrict__ bv,
    _Float16* __restrict__ Oq, _Float16* __restrict__ kT, _Float16* __restrict__ vT) {
    constexpr int K = 512;
    constexpr int NITER = K / 32;

    __shared__ __align__(16) unsigned short As[2][128 * 32];
    __shared__ __align__(16) unsigned short Bs[2][128 * 32];

    const int t = threadIdx.x;
    const int did = blockIdx.x + 6 * blockIdx.y;
    const int lid = (did & 7) * 384 + (did >> 3);
    const int bx = lid % 6;
    const int Mb = (lid / 6) * 128;
    const int nrow0 = bx * 128;

    const int lane = t & 63;
    const int wv = t >> 6;
    const int mq = (wv >> 1) * 64;
    const int nq = (wv & 1) * 64;
    const int mrow = lane & 15;
    const int kq = lane >> 4;
    const int fragoff = mrow * 32 + ((kq ^ ((mrow >> 1) & 3)) * 8);

    const unsigned char *asrc0, *asrc1, *bsrc0, *bsrc1;
    int off0, off1;
    {
        int cid0 = t, cid1 = t + 256;
        int m0 = cid0 >> 2, c0 = (cid0 & 3) ^ ((m0 >> 1) & 3);
        int m1 = cid1 >> 2, c1 = (cid1 & 3) ^ ((m1 >> 1) & 3);
        asrc0 = (const unsigned char*)(A16 + (size_t)(Mb + m0) * K + c0 * 8);
        asrc1 = (const unsigned char*)(A16 + (size_t)(Mb + m1) * K + c1 * 8);
        bsrc0 = (const unsigned char*)(Bw + (size_t)(nrow0 + m0) * K + c0 * 8);
        bsrc1 = (const unsigned char*)(Bw + (size_t)(nrow0 + m1) * K + c1 * 8);
        off0 = cid0 * 8;
        off1 = cid1 * 8;
    }

    f32x4 acc[4][4];
#pragma unroll
    for (int mi = 0; mi < 4; mi++)
#pragma unroll
        for (int ni = 0; ni < 4; ni++) acc[mi][ni] = (f32x4){0.f, 0.f, 0.f, 0.f};

    gld16(asrc0, &As[0][off0]);
    gld16(asrc1, &As[0][off1]);
    gld16(bsrc0, &Bs[0][off0]);
    gld16(bsrc1, &Bs[0][off1]);
    __syncthreads();

    int cur = 0;
#pragma unroll 1
    for (int it = 0; it < NITER; ++it) {
        if (it + 1 < NITER) {
            gld16(asrc0 + (it + 1) * 64, &As[cur ^ 1][off0]);
            gld16(asrc1 + (it + 1) * 64, &As[cur ^ 1][off1]);
            gld16(bsrc0 + (it + 1) * 64, &Bs[cur ^ 1][off0]);
            gld16(bsrc1 + (it + 1) * 64, &Bs[cur ^ 1][off1]);
        }

        half8 ah[4], bh[4];
#pragma unroll
        for (int mi = 0; mi < 4; mi++)
            ah[mi] = *(const half8*)&As[cur][(mq + mi * 16) * 32 + fragoff];
#pragma unroll
        for (int ni = 0; ni < 4; ni++)
            bh[ni] = *(const half8*)&Bs[cur][(nq + ni * 16) * 32 + fragoff];
#pragma unroll
        for (int mi = 0; mi < 4; mi++)
#pragma unroll
            for (int ni = 0; ni < 4; ni++)
                acc[mi][ni] = __builtin_amdgcn_mfma_f32_16x16x32_f16(ah[mi], bh[ni], acc[mi][ni], 0, 0, 0);

        if (it + 1 < NITER) __syncthreads();
        cur ^= 1;
    }

#pragma unroll
    for (int ni = 0; ni < 4; ni++) {
        int gc = nrow0 + nq + ni * 16 + mrow;
        int mat = gc >> 8;
        int col = gc & 255;
        float bb = (mat == 0 ? bq : mat == 1 ? bk : bv)[col];
        if (mat == 0) {
#pragma unroll
            for (int mi = 0; mi < 4; mi++)
#pragma unroll
                for (int r = 0; r < 4; r++) {
                    int m = Mb + mq + mi * 16 + kq * 4 + r;
                    float v2 = fmaxf(acc[mi][ni][r] + bb, 0.f);
                    Oq[(size_t)m * CF_ + col] = (_Float16)v2;
                }
        } else {
            _Float16* OT = (mat == 1) ? kT : vT;
#pragma unroll
            for (int mi = 0; mi < 4; mi++) {
                int m0r = Mb + mq + mi * 16 + kq * 4;
                half4 hv;
#pragma unroll
                for (int r = 0; r < 4; r++) {
                    float v2 = acc[mi][ni][r] + bb;
                    if (mat == 1) v2 = fmaxf(v2, 0.f);
                    hv[r] = (_Float16)v2;
                }
                *(half4*)&OT[(size_t)col * BN_ + m0r] = hv;
            }
        }
    }
}

// ---------------------------------------------------------------- output projection GEMM
__global__ __launch_bounds__(256) void gemm_out(
    const _Float16* __restrict__ A16, const _Float16* __restrict__ Bw,
    const float* __restrict__ bo, const float* __restrict__ sg,
    float* __restrict__ Of) {
    constexpr int K = 256;
    constexpr int NITER = K / 32;

    __shared__ __align__(16) unsigned short As[2][128 * 32];
    __shared__ __align__(16) unsigned short Bs[2][128 * 32];

    const int t = threadIdx.x;
    const int did = blockIdx.x + 4 * blockIdx.y;
    const int lid = (did & 7) * 256 + (did >> 3);
    const int bx = lid & 3;
    const int Mb = (lid >> 2) * 128;
    const int nrow0 = bx * 128;

    const int lane = t & 63;
    const int wv = t >> 6;
    const int mq = (wv >> 1) * 64;
    const int nq = (wv & 1) * 64;
    const int mrow = lane & 15;
    const int kq = lane >> 4;
    const int fragoff = mrow * 32 + ((kq ^ ((mrow >> 1) & 3)) * 8);

    const unsigned char *asrc0, *asrc1, *bsrc0, *bsrc1;
    int off0, off1;
    {
        int cid0 = t, cid1 = t + 256;
        int m0 = cid0 >> 2, c0 = (cid0 & 3) ^ ((m0 >> 1) & 3);
        int m1 = cid1 >> 2, c1 = (cid1 & 3) ^ ((m1 >> 1) & 3);
        asrc0 = (const unsigned char*)(A16 + (size_t)(Mb + m0) * K + c0 * 8);
        asrc1 = (const unsigned char*)(A16 + (size_t)(Mb + m1) * K + c1 * 8);
        bsrc0 = (const unsigned char*)(Bw + (size_t)(nrow0 + m0) * K + c0 * 8);
        bsrc1 = (const unsigned char*)(Bw + (size_t)(nrow0 + m1) * K + c1 * 8);
        off0 = cid0 * 8;
        off1 = cid1 * 8;
    }

    f32x4 acc[4][4];
#pragma unroll
    for (int mi = 0; mi < 4; mi++)
#pragma unroll
        for (int ni = 0; ni < 4; ni++) acc[mi][ni] = (f32x4){0.f, 0.f, 0.f, 0.f};

    gld16(asrc0, &As[0][off0]);
    gld16(asrc1, &As[0][off1]);
    gld16(bsrc0, &Bs[0][off0]);
    gld16(bsrc1, &Bs[0][off1]);
    __syncthreads();

    int cur = 0;
#pragma unroll 1
    for (int it = 0; it < NITER; ++it) {
        if (it + 1 < NITER) {
            gld16(asrc0 + (it + 1) * 64, &As[cur ^ 1][off0]);
            gld16(asrc1 + (it + 1) * 64, &As[cur ^ 1][off1]);
            gld16(bsrc0 + (it + 1) * 64, &Bs[cur ^ 1][off0]);
            gld16(bsrc1 + (it + 1) * 64, &Bs[cur ^ 1][off1]);
        }

        half8 ah[4], bh[4];
#pragma unroll
        for (int mi = 0; mi < 4; mi++)
            ah[mi] = *(const half8*)&As[cur][(mq + mi * 16) * 32 + fragoff];
#pragma unroll
        for (int ni = 0; ni < 4; ni++)
            bh[ni] = *(const half8*)&Bs[cur][(nq + ni * 16) * 32 + fragoff];
#pragma unroll
        for (int mi = 0; mi < 4; mi++)
#pragma unroll
            for (int ni = 0; ni < 4; ni++)
                acc[mi][ni] = __builtin_amdgcn_mfma_f32_16x16x32_f16(ah[mi], bh[ni], acc[mi][ni], 0, 0, 0);

        if (it + 1 < NITER) __syncthreads();
        cur ^= 1;
    }

    int b = Mb >> 12;
#pragma unroll
    for (int ni = 0; ni < 4; ni++) {
        int gc = nrow0 + nq + ni * 16 + mrow;
        float bb = bo[gc];
        float gv = sg[b * C_ + gc];
#pragma unroll
        for (int mi = 0; mi < 4; mi++)
#pragma unroll
            for (int r = 0; r < 4; r++) {
                int m = Mb + mq + mi * 16 + kq * 4 + r;
                float v2 = abs_clamp(acc[mi][ni][r] + bb);
                v2 = abs_clamp(v2 * (1.f + gv));
                Of[(size_t)m * C_ + gc] = v2;
            }
    }
}

// ---------------------------------------------------------------- kv state + k_sum via f16 MFMA
// 128-token chunks per LDS phase (half the barriers of the 64-token version).
// Inputs TRANSPOSED [col=256][M=65536]; output kvout [b][h][d=32][f=128].
__global__ __launch_bounds__(256) void kv_mfma_kernel(const _Float16* __restrict__ kin,
                                                      const _Float16* __restrict__ vin,
                                                      float* __restrict__ kvout,
                                                      float* __restrict__ ksum) {
    __shared__ __align__(16) unsigned short Ah[128 * 128];   // 32 KB
    __shared__ __align__(16) unsigned short Bh[48 * 128];    // 12 KB

    const int t = threadIdx.x;
    const int c8 = blockIdx.x;           // 512-token slab
    const int h = blockIdx.y, b = blockIdx.z;
    const int dp = t & 31;               // channel within head
    const int oct = t >> 5;              // token octet 0..7 (handles oct and oct+8)

    // constant rows 32..47: row 32 = ones(f16), rest zero (written once)
    {
        int r = 32 + (t >> 4);
        int c = t & 15;
        unsigned short fill = (r == 32) ? (unsigned short)0x3C00 : (unsigned short)0;
        u16x8 z = {fill, fill, fill, fill, fill, fill, fill, fill};
        *(u16x8*)&Bh[r * 128 + ((c ^ (r & 7)) * 8)] = z;
    }

    float cbv[8], sbv[8];
#pragma unroll
    for (int i = 0; i < 8; i++) {
        float ang = (PI2F / 64.f) * (float)(oct * 8 + i);
        cbv[i] = cosf(ang);
        sbv[i] = sinf(ang);
    }

    const int lane = t & 63;
    const int wv = t >> 6;
    const int mrow = lane & 15;
    const int kq = lane >> 4;

    f32x4 acc[2][3];
#pragma unroll
    for (int mi = 0; mi < 2; mi++)
#pragma unroll
        for (int ni = 0; ni < 3; ni++) acc[mi][ni] = (f32x4){0.f, 0.f, 0.f, 0.f};

    int offAa[4], offAb[4];
#pragma unroll
    for (int tvar = 0; tvar < 4; tvar++) {
        int f = tvar * 32 + dp;
        offAa[tvar] = f * 128 + ((oct ^ (f & 7)) * 8);
        offAb[tvar] = f * 128 + (((oct + 8) ^ (f & 7)) * 8);
    }
    const int offBa = dp * 128 + ((oct ^ (dp & 7)) * 8);
    const int offBb = dp * 128 + (((oct + 8) ^ (dp & 7)) * 8);

    const size_t colbase = (size_t)(h * HD_ + dp) * BN_ + (size_t)b * N_;

#pragma unroll 1
    for (int ch = 0; ch < 4; ch++) {
        const int n0 = c8 * 512 + ch * 128;
        const int rr = n0 >> 6;
        float ca0 = cosf((PI2F / 64.f) * (float)rr),       sa0 = sinf((PI2F / 64.f) * (float)rr);
        float ca1 = cosf((PI2F / 64.f) * (float)(rr + 1)), sa1 = sinf((PI2F / 64.f) * (float)(rr + 1));

        const _Float16* kp = kin + colbase + n0 + oct * 8;
        const _Float16* vp = vin + colbase + n0 + oct * 8;
        half8 k8a = *(const half8*)kp;
        half8 k8b = *(const half8*)(kp + 64);
        half8 v8a = *(const half8*)vp;
        half8 v8b = *(const half8*)(vp + 64);
        float ka[8], kb[8];
#pragma unroll
        for (int i = 0; i < 8; i++) { ka[i] = (float)k8a[i]; kb[i] = (float)k8b[i]; }

        __syncthreads();   // previous chunk's fragment reads done

#pragma unroll
        for (int tvar = 0; tvar < 4; tvar++) {
            half8 ha, hb;
#pragma unroll
            for (int i = 0; i < 8; i++) {
                float fa = (tvar == 0) ? ca0 : (tvar == 1) ? sa0 : (tvar == 2) ? cbv[i] : sbv[i];
                float fb = (tvar == 0) ? ca1 : (tvar == 1) ? sa1 : (tvar == 2) ? cbv[i] : sbv[i];
                ha[i] = (_Float16)(ka[i] * fa);
                hb[i] = (_Float16)(kb[i] * fb);
            }
            *(half8*)&Ah[offAa[tvar]] = ha;
            *(half8*)&Ah[offAb[tvar]] = hb;
        }
        *(half8*)&Bh[offBa] = v8a;
        *(half8*)&Bh[offBb] = v8b;
        __syncthreads();

#pragma unroll
        for (int s = 0; s < 4; s++) {
            int koct = s * 4 + kq;
            half8 ah[2], bh[3];
#pragma unroll
            for (int mi = 0; mi < 2; mi++) {
                int f = (wv * 2 + mi) * 16 + mrow;
                ah[mi] = *(const half8*)&Ah[f * 128 + ((koct ^ (f & 7)) * 8)];
            }
#pragma unroll
            for (int ni = 0; ni < 3; ni++) {
                int nr = ni * 16 + mrow;
                bh[ni] = *(const half8*)&Bh[nr * 128 + ((koct ^ (nr & 7)) * 8)];
            }
#pragma unroll
            for (int mi = 0; mi < 2; mi++)
#pragma unroll
                for (int ni = 0; ni < 3; ni++)
                    acc[mi][ni] = __builtin_amdgcn_mfma_f32_16x16x32_f16(ah[mi], bh[ni], acc[mi][ni], 0, 0, 0);
        }
    }

    // transposed store: kvout[b][h][d][f]
    float* kvp = kvout + (size_t)(b * NH_ + h) * FHD_ * HD_;
    float* ksp = ksum + (size_t)(b * NH_ + h) * FHD_;
#pragma unroll
    for (int mi = 0; mi < 2; mi++) {
        int mt = wv * 2 + mi;
#pragma unroll
        for (int r = 0; r < 4; r++) {
            int f = mt * 16 + kq * 4 + r;
            atomicAdd(&kvp[(size_t)mrow * FHD_ + f], acc[mi][0][r]);
            atomicAdd(&kvp[(size_t)(16 + mrow) * FHD_ + f], acc[mi][1][r]);
            if (mrow == 0) atomicAdd(&ksp[f], acc[mi][2][r]);
        }
    }
}

// ---------------------------------------------------------------- attention lookup via MFMA -> f16
// Factored form: out(n,d) = sum_t trig_t(n) * (q(n,:) . kv_t(:,d)).
// A = RAW q [128 tok][32] (staging = pure copy), 4 separate K=32 accumulators
// (acc[t]), trig folded in the epilogue. B rows 0..31 = abs_clamp(KV^T) f16,
// row 32 = ksum (z-denominator for free), rows 33..47 zero.
__global__ __launch_bounds__(256) void attn_kernel(const _Float16* __restrict__ qbuf,
                                                   const float* __restrict__ kvin,
                                                   const float* __restrict__ ksum,
                                                   _Float16* __restrict__ ob) {
    __shared__ __align__(16) unsigned short Aq[128 * 40];    // [tok][32] pad->40 (bank spread)
    __shared__ __align__(16) unsigned short Bk[48 * 128];    // 12 KB
    __shared__ __align__(16) float tS[128][4];
    __shared__ float zS[128];

    const int chunk = blockIdx.x;
    const int h = blockIdx.y, b = blockIdx.z;
    const int t = threadIdx.x;
    const int n0 = chunk * 128;

    // ---- stage B
    {
        const float* kvp = kvin + ((size_t)(b * NH_ + h)) * (HD_ * FHD_);
        int d = t >> 3;            // 0..31
        int c0 = (t & 7) * 2;
#pragma unroll
        for (int cc = 0; cc < 2; cc++) {
            int c = c0 + cc;
            const float* src = kvp + (size_t)d * FHD_ + c * 8;
            half8 hv;
#pragma unroll
            for (int i = 0; i < 8; i++) hv[i] = (_Float16)abs_clamp(src[i]);
            *(half8*)&Bk[d * 128 + ((c ^ (d & 7)) * 8)] = hv;
        }
        if (t < 16) {
            const float* ks = ksum + ((size_t)(b * NH_ + h)) * FHD_ + t * 8;
            half8 hv;
#pragma unroll
            for (int i = 0; i < 8; i++) hv[i] = (_Float16)ks[i];
            *(half8*)&Bk[32 * 128 + (t * 8)] = hv;         // 32&7==0
        } else {
            int idx = t - 16;                               // 240 chunks, rows 33..47
            int r = 33 + (idx >> 4), c = idx & 15;
            half8 z = {};
            *(half8*)&Bk[r * 128 + ((c ^ (r & 7)) * 8)] = z;
        }
    }
    // ---- stage A: raw q, pure copy
    {
        int tok = t >> 1, hf = t & 1;
        const _Float16* qp = qbuf + ((size_t)b * N_ + n0 + tok) * CF_ + h * HD_ + hf * 16;
        half8 a0 = *(const half8*)qp;
        half8 a1 = *(const half8*)(qp + 8);
        *(half8*)&Aq[tok * 40 + hf * 16] = a0;
        *(half8*)&Aq[tok * 40 + hf * 16 + 8] = a1;
    }
    // ---- trig table
    if (t < 128) {
        int n = n0 + t;
        float aa = (PI2F / 64.f) * (float)(n >> 6);
        float ab = (PI2F / 64.f) * (float)(n & 63);
        tS[t][0] = cosf(aa); tS[t][1] = sinf(aa);
        tS[t][2] = cosf(ab); tS[t][3] = sinf(ab);
    }
    __syncthreads();

    const int lane = t & 63;
    const int wv = t >> 6;            // wave handles tokens [wv*32, wv*32+32)
    const int mrow = lane & 15;
    const int kq = lane >> 4;

    // A fragments are t-invariant: 2 ds_reads total
    half8 ah[2];
#pragma unroll
    for (int mi = 0; mi < 2; mi++)
        ah[mi] = *(const half8*)&Aq[(wv * 32 + mi * 16 + mrow) * 40 + kq * 8];

    f32x4 acc[4][2][3];
#pragma unroll
    for (int tt = 0; tt < 4; tt++)
#pragma unroll
        for (int mi = 0; mi < 2; mi++)
#pragma unroll
            for (int ni = 0; ni < 3; ni++) acc[tt][mi][ni] = (f32x4){0.f, 0.f, 0.f, 0.f};

#pragma unroll
    for (int tt = 0; tt < 4; tt++) {
        half8 bh[3];
        int cpos = tt * 4 + kq;
#pragma unroll
        for (int ni = 0; ni < 3; ni++) {
            int row = ni * 16 + mrow;
            bh[ni] = *(const half8*)&Bk[row * 128 + ((cpos ^ (row & 7)) * 8)];
        }
#pragma unroll
        for (int mi = 0; mi < 2; mi++)
#pragma unroll
            for (int ni = 0; ni < 3; ni++)
                acc[tt][mi][ni] = __builtin_amdgcn_mfma_f32_16x16x32_f16(ah[mi], bh[ni], acc[tt][mi][ni], 0, 0, 0);
    }

    // z: C column 32 (ni=2, col offset 0) -> lanes with mrow==0; combine with trig
    if (mrow == 0) {
#pragma unroll
        for (int mi = 0; mi < 2; mi++)
#pragma unroll
            for (int r = 0; r < 4; r++) {
                int tok = wv * 32 + mi * 16 + kq * 4 + r;
                float4 tv = *(const float4*)&tS[tok][0];
                float zraw = tv.x * acc[0][mi][2][r] + tv.y * acc[1][mi][2][r]
                           + tv.z * acc[2][mi][2][r] + tv.w * acc[3][mi][2][r];
                zS[tok] = abs_clamp(1.f / (zraw + EPS_));
            }
    }
    __syncthreads();

#pragma unroll
    for (int mi = 0; mi < 2; mi++) {
#pragma unroll
        for (int r = 0; r < 4; r++) {
            int tok = wv * 32 + mi * 16 + kq * 4 + r;
            float4 tv = *(const float4*)&tS[tok][0];
            float z = zS[tok];
            float v0 = tv.x * acc[0][mi][0][r] + tv.y * acc[1][mi][0][r]
                     + tv.z * acc[2][mi][0][r] + tv.w * acc[3][mi][0][r];
            float v1 = tv.x * acc[0][mi][1][r] + tv.y * acc[1][mi][1][r]
                     + tv.z * acc[2][mi][1][r] + tv.w * acc[3][mi][1][r];
            v0 = abs_clamp(abs_clamp(v0) * z);
            v1 = abs_clamp(abs_clamp(v1) * z);
            size_t base = ((size_t)b * N_ + n0 + tok) * CF_ + h * HD_;
            ob[base + mrow] = (_Float16)v0;
            ob[base + 16 + mrow] = (_Float16)v1;
        }
    }
}

// ----------------------------------------------------------------
extern "C" void kernel_launch(void* const* d_in, const int* in_sizes, int n_in,
                              void* d_out, int out_size, void* d_ws, size_t ws_size,
                              hipStream_t stream) {
    (void)in_sizes; (void)n_in; (void)out_size; (void)ws_size;
    const float* query = (const float*)d_in[0];
    const float* Wq = (const float*)d_in[1];
    const float* bq = (const float*)d_in[2];
    const float* Wk = (const float*)d_in[3];
    const float* bk = (const float*)d_in[4];
    const float* Wv = (const float*)d_in[5];
    const float* bv = (const float*)d_in[6];
    const float* Wo = (const float*)d_in[7];
    const float* bo = (const float*)d_in[8];
    const float* Wse1 = (const float*)d_in[9];
    const float* Wse2 = (const float*)d_in[10];
    float* out = (float*)d_out;

    unsigned char* ws = (unsigned char*)d_ws;
    const size_t MB = 1024ull * 1024ull;
    // q16 [65536,512] f16 @0 (64 MiB). Dead after gemm_qkv; ob [65536,256] f16
    // aliased onto it (attn runs strictly after gemm_qkv; single stream).
    _Float16* q16 = (_Float16*)(ws + 0);
    _Float16* ob  = (_Float16*)(ws + 0);
    _Float16* qb  = (_Float16*)(ws + 64 * MB);   // [65536,256] f16
    _Float16* kbT = (_Float16*)(ws + 96 * MB);   // [256,65536] f16 (transposed)
    _Float16* vbT = (_Float16*)(ws + 128 * MB);  // [256,65536] f16 (transposed)
    _Float16* wcat = (_Float16*)(ws + 160 * MB);            // [768,512] f16
    _Float16* wo16 = (_Float16*)(ws + 160 * MB + 786432);   // [512,256] f16
    float* kvb = (float*)(ws + 161 * MB);                   // [16,8,32,128] f32
    float* ksb = (float*)(ws + 163 * MB);                   // [16,8,128]
    float* ssb = (float*)(ws + 163 * MB + 65536);           // [16,512]
    float* sgb = (float*)(ws + 163 * MB + 98304);           // [16,512]

    hipMemsetAsync(kvb, 0, 2097152 + 65536 + 32768, stream);

    convert_w<<<2048, 256, 0, stream>>>(Wq, Wk, Wv, Wo, wcat, wo16);
    se_sum_kernel<<<dim3(B_, 64), 256, 0, stream>>>(query, ssb, q16);
    se_gate_kernel<<<B_, 256, 0, stream>>>(ssb, Wse1, Wse2, sgb);
    gemm_qkv<<<dim3(6, 512), 256, 0, stream>>>(q16, wcat, bq, bk, bv, qb, kbT, vbT);
    kv_mfma_kernel<<<dim3(8, NH_, B_), 256, 0, stream>>>(kbT, vbT, kvb, ksb);
    attn_kernel<<<dim3(32, NH_, B_), 256, 0, stream>>>(qb, kvb, ksb, ob);
    gemm_out<<<dim3(4, 512), 256, 0, stream>>>(ob, wo16, bo, sgb, out);
}